// Round 7
// baseline (203.128 us; speedup 1.0000x reference)
//
#include <hip/hip_runtime.h>

typedef float f32x4 __attribute__((ext_vector_type(4)));
typedef short s16x8 __attribute__((ext_vector_type(8)));
typedef unsigned short us4 __attribute__((ext_vector_type(4)));

#define MFMA16(a, b, c) __builtin_amdgcn_mfma_f32_16x16x32_bf16(a, b, c, 0, 0, 0)

// async global->LDS DMA, 16B per lane. LDS dest must be wave-uniform base + lane*16.
#define GLOAD_LDS16(gp, lp) __builtin_amdgcn_global_load_lds( \
    (__attribute__((address_space(1))) void*)(gp),            \
    (__attribute__((address_space(3))) void*)(lp), 16, 0, 0)

__device__ __forceinline__ unsigned short f2bf(float f) {
    union { float f; unsigned u; } v; v.f = f;
    unsigned r = v.u + 0x7fffu + ((v.u >> 16) & 1u);   // RNE truncate to bf16
    return (unsigned short)(r >> 16);
}

// Repack tile row stride: 136 shorts = 272B (16B-aligned rows, odd-ish bank
// stride so scalar ds_writes are ~2-way and b128 readback ~4-way).
#define RP 136
// shared for 128x128 GEMM kernels: pipeline-3 needs 3*8192 = 24576 shorts
// (49152B); repack needs 128*RP = 17408 shorts — aliased into the same array.
#define SH128 24576

// ---------------------------------------------------------------------------
// Depth-3 counted-vmcnt GEMM core, 128x128 tile: C += A[128xK] @ B[128xK]^T.
// Three 8192-short buffers; loads get TWO full iterations (+barriers) to land.
//   iter i: rem>=2 -> vmcnt(8) (tile i landed, 2 tiles in flight)
//           barrier; ds_read buf[i%3]; lgkmcnt(0)+sched_barrier; 16 MFMA
//           barrier; issue tile i+3 -> buf[i%3]
// Invariants: buf[cur] rewritten only after barrier B of iter i (all reads
// retired); its next read is 2 iters later behind a counted wait. Verified
// skeleton from R6 (passed), one more buffer.
// Ends with vmcnt==0 and a trailing barrier -> callers may reuse sh.
// ---------------------------------------------------------------------------
__device__ __forceinline__ void gemm_core128_p3(
    const unsigned short* __restrict__ Ab, size_t Astride,
    const unsigned short* __restrict__ Bb, size_t Bstride,
    int K, unsigned short* sh, int t, f32x4 acc[4][4])
{
    const int wave = t >> 6, lane = t & 63;
    const int c = lane & 15, quad = lane >> 4;
    const int wm = (wave >> 1) * 64, wn = (wave & 1) * 64;
    const int srow = t >> 2;
    const int scol = (t & 3) * 8;

    const unsigned short* ga = Ab + (size_t)srow * Astride + scol;
    const unsigned short* gb = Bb + (size_t)srow * Bstride + scol;
    const int nt = K >> 5;

    for (int p = 0; p < 3 && p < nt; p++) {        // prologue: tiles 0..2
        unsigned short* nb = sh + p * 8192;
        GLOAD_LDS16(ga + p * 32,                 nb + t * 8);
        GLOAD_LDS16(ga + p * 32 + 64 * Astride,  nb + 2048 + t * 8);
        GLOAD_LDS16(gb + p * 32,                 nb + 4096 + t * 8);
        GLOAD_LDS16(gb + p * 32 + 64 * Bstride,  nb + 6144 + t * 8);
    }

    int cur = 0;
    for (int i = 0; i < nt; i++) {
        int rem = nt - 1 - i;
        if (rem >= 2)      asm volatile("s_waitcnt vmcnt(8)" ::: "memory");
        else if (rem == 1) asm volatile("s_waitcnt vmcnt(4)" ::: "memory");
        else               asm volatile("s_waitcnt vmcnt(0)" ::: "memory");
        __builtin_amdgcn_s_barrier();              // tile i visible to all
        __builtin_amdgcn_sched_barrier(0);

        const unsigned short* buf = sh + cur * 8192;
        s16x8 af[4], bf[4];
        #pragma unroll
        for (int q = 0; q < 4; q++)
            af[q] = *(const s16x8*)(buf + (wm + q * 16 + c) * 32 + quad * 8);
        #pragma unroll
        for (int q = 0; q < 4; q++)
            bf[q] = *(const s16x8*)(buf + 4096 + (wn + q * 16 + c) * 32 + quad * 8);

        asm volatile("s_waitcnt lgkmcnt(0)" ::: "memory");
        __builtin_amdgcn_sched_barrier(0);         // rule #18: pin MFMA below

        #pragma unroll
        for (int mt = 0; mt < 4; mt++)
            #pragma unroll
            for (int ntl = 0; ntl < 4; ntl++)
                acc[mt][ntl] = MFMA16(af[mt], bf[ntl], acc[mt][ntl]);

        __builtin_amdgcn_s_barrier();              // all reads of buf retired
        __builtin_amdgcn_sched_barrier(0);

        if (i + 3 < nt) {                          // tile i+3 -> freed buf
            unsigned short* nb = sh + cur * 8192;
            int kk = (i + 3) * 32;
            GLOAD_LDS16(ga + kk,                 nb + t * 8);
            GLOAD_LDS16(ga + kk + 64 * Astride,  nb + 2048 + t * 8);
            GLOAD_LDS16(gb + kk,                 nb + 4096 + t * 8);
            GLOAD_LDS16(gb + kk + 64 * Bstride,  nb + 6144 + t * 8);
        }
        cur = (cur == 2) ? 0 : cur + 1;
    }
}

// ---------------------------------------------------------------------------
// prior: one WAVE per (b,i) row — no LDS, no barriers, no atomics.
// ---------------------------------------------------------------------------
__device__ __forceinline__ void prior_wave(
    const float* __restrict__ x, const float* __restrict__ wsv,
    float* __restrict__ pout, int row, int lane)
{
    const float4* xr = (const float4*)(x + (size_t)row * 512);
    const float4* wr = (const float4*)wsv;
    float4 a0 = xr[lane * 2],     b0 = wr[lane * 2];
    float4 a1 = xr[lane * 2 + 1], b1 = wr[lane * 2 + 1];
    float part = a0.x * b0.x + a0.y * b0.y + a0.z * b0.z + a0.w * b0.w
               + a1.x * b1.x + a1.y * b1.y + a1.z * b1.z + a1.w * b1.w;
    #pragma unroll
    for (int o = 32; o; o >>= 1) part += __shfl_xor(part, o, 64);
    float sigma = part;
    float inv2 = 0.5f / (sigma * sigma);

    int i = row & 2047;
    float g[32];
    float sum = 0.f;
    #pragma unroll
    for (int u = 0; u < 8; u++) {
        #pragma unroll
        for (int v = 0; v < 4; v++) {
            float d = (float)(u * 256 + lane * 4 + v - i);
            float e = __expf(-(d * d) * inv2);
            g[u * 4 + v] = e;
            sum += e;
        }
    }
    #pragma unroll
    for (int o = 32; o; o >>= 1) sum += __shfl_xor(sum, o, 64);
    float inv = 1.0f / sum;

    float4* pr = (float4*)(pout + (size_t)row * 2048);
    #pragma unroll
    for (int u = 0; u < 8; u++) {
        float4 o4 = { g[u * 4] * inv, g[u * 4 + 1] * inv,
                      g[u * 4 + 2] * inv, g[u * 4 + 3] * inv };
        pr[u * 64 + lane] = o4;
    }
}

// ---------------------------------------------------------------------------
// conversion bodies (verified R4 logic)
// ---------------------------------------------------------------------------
__device__ __forceinline__ void convert_body(
    const float* __restrict__ x, const float* __restrict__ wq,
    const float* __restrict__ wk, const float* __restrict__ wv,
    unsigned short* __restrict__ xbf, unsigned short* __restrict__ wt,
    int bid, int t, unsigned short (*lt)[72])
{
    if (bid < 4096) {
        int gid = bid * 256 + t;
        float4 v = ((const float4*)x)[gid];
        us4 o = { f2bf(v.x), f2bf(v.y), f2bf(v.z), f2bf(v.w) };
        ((us4*)xbf)[gid] = o;
    } else {
        int idx = bid - 4096;
        int w = idx >> 6;                    // 0=q 1=k 2=v
        int tile = idx & 63;
        int tk = tile >> 3, tn = tile & 7;   // 8x8 tiles of 64x64 over [512][512]
        const float* src = ((w == 0) ? wq : (w == 1) ? wk : wv)
                         + (size_t)(tk * 64) * 512 + tn * 64;

        int row = t >> 2;
        int c0 = (t & 3) * 16;
        const float4* s = (const float4*)(src + (size_t)row * 512 + c0);
        #pragma unroll
        for (int q = 0; q < 4; q++) {
            float4 v = s[q];
            lt[c0 + q * 4 + 0][row] = f2bf(v.x);
            lt[c0 + q * 4 + 1][row] = f2bf(v.y);
            lt[c0 + q * 4 + 2][row] = f2bf(v.z);
            lt[c0 + q * 4 + 3][row] = f2bf(v.w);
        }
        __syncthreads();

        int n = t >> 2;
        int k0 = (t & 3) * 16;
        s16x8 a = *(const s16x8*)&lt[n][k0];
        s16x8 b = *(const s16x8*)&lt[n][k0 + 8];
        unsigned short* dst = wt + (((size_t)(w * 512 + tn * 64 + n)) << 9)
                                 + tk * 64 + k0;
        *(s16x8*)dst = a;
        *(s16x8*)(dst + 8) = b;
    }
}

// Kernel 1a (ws path): convert + prior merged. Grid 6336:
// [0,4288) convert (as before), [4288,6336) prior (4 rows/block, wave-per-row).
// Prior depends only on x and writes pout (disjoint) -> free overlap here
// instead of serializing at the score kernel's tail.
__global__ __launch_bounds__(256) void k_convert_prior(
    const float* __restrict__ x, const float* __restrict__ wq,
    const float* __restrict__ wk, const float* __restrict__ wv,
    unsigned short* __restrict__ xbf, unsigned short* __restrict__ wt,
    const float* __restrict__ wsv, float* __restrict__ pout)
{
    __shared__ __align__(16) unsigned short lt[64][72];
    int bid = blockIdx.x, t = threadIdx.x;
    if (bid < 4288) {
        convert_body(x, wq, wk, wv, xbf, wt, bid, t, lt);
    } else {
        int row = (bid - 4288) * 4 + (t >> 6);
        prior_wave(x, wsv, pout, row, t & 63);
    }
}

// Kernel 1b (fallback): convert only. Grid 4288.
__global__ __launch_bounds__(256) void k_convert(
    const float* __restrict__ x, const float* __restrict__ wq,
    const float* __restrict__ wk, const float* __restrict__ wv,
    unsigned short* __restrict__ xbf, unsigned short* __restrict__ wt)
{
    __shared__ __align__(16) unsigned short lt[64][72];
    convert_body(x, wq, wk, wv, xbf, wt, blockIdx.x, threadIdx.x, lt);
}

// ---------------------------------------------------------------------------
// Kernel 2: QKV projection. [8192x512] @ [1536x512]^T. Grid 768 (1D).
// XCD-chunked swizzle (768%8==0): each XCD gets 8 m-tiles x all 12 n-tiles ->
// A-panel 1MB + B 1.5MB fits its 4MB L2. Epilogues repack through LDS.
// ---------------------------------------------------------------------------
__global__ __launch_bounds__(256) void k_proj(
    const unsigned short* __restrict__ xbf, const unsigned short* __restrict__ wt,
    unsigned short* __restrict__ qbf, unsigned short* __restrict__ kbf,
    unsigned short* __restrict__ vtbf)
{
    __shared__ __align__(16) unsigned short sh[SH128];

    int t = threadIdx.x;
    int lin = blockIdx.x;
    int sw = (lin & 7) * 96 + (lin >> 3);         // bijective, 96 blocks/XCD
    int mt_ = sw / 12, nt_ = sw % 12;
    int m0 = mt_ * 128, n0 = nt_ * 128;
    f32x4 acc[4][4] = {};

    gemm_core128_p3(xbf + (size_t)m0 * 512, 512, wt + (size_t)n0 * 512, 512,
                    512, sh, t, acc);
    // core ends with a barrier + vmcnt drained; sh is reusable now

    int wave = t >> 6, lane = t & 63, c = lane & 15, quad = lane >> 4;
    int wm = (wave >> 1) * 64, wn = (wave & 1) * 64;
    int sel = nt_ >> 2;                           // 0=q 1=k 2=v

    if (sel < 2) {
        unsigned short* dst = sel ? kbf : qbf;
        int ncol0 = n0 - sel * 512;
        #pragma unroll
        for (int mt = 0; mt < 4; mt++)
            #pragma unroll
            for (int nt = 0; nt < 4; nt++)
                #pragma unroll
                for (int r = 0; r < 4; r++)
                    sh[(wm + mt * 16 + quad * 4 + r) * RP + wn + nt * 16 + c]
                        = f2bf(acc[mt][nt][r]);
        __syncthreads();
        int rr = t >> 1, hh = (t & 1) * 64;
        const s16x8* sp = (const s16x8*)(sh + rr * RP + hh);
        s16x8* dp = (s16x8*)(dst + (size_t)(m0 + rr) * 512 + ncol0 + hh);
        s16x8 v[8];
        #pragma unroll
        for (int i = 0; i < 8; i++) v[i] = sp[i];
        #pragma unroll
        for (int i = 0; i < 8; i++) dp[i] = v[i];
    } else {
        // V: repack transposed in LDS -> 128B-contiguous stores per thread.
        #pragma unroll
        for (int mt = 0; mt < 4; mt++)
            #pragma unroll
            for (int nt = 0; nt < 4; nt++)
                #pragma unroll
                for (int r = 0; r < 4; r++)
                    sh[(wn + nt * 16 + c) * RP + wm + mt * 16 + quad * 4 + r]
                        = f2bf(acc[mt][nt][r]);
        __syncthreads();
        int bb = m0 >> 11, nn0 = m0 & 2047;
        int dbase = n0 - 1024;
        int dl = t >> 1, nh = (t & 1) * 64;
        const s16x8* sp = (const s16x8*)(sh + dl * RP + nh);
        s16x8* dp = (s16x8*)(vtbf + ((size_t)(bb * 512 + dbase + dl)) * 2048
                                  + nn0 + nh);
        s16x8 v[8];
        #pragma unroll
        for (int i = 0; i < 8; i++) v[i] = sp[i];
        #pragma unroll
        for (int i = 0; i < 8; i++) dp[i] = v[i];
    }
}

// ---------------------------------------------------------------------------
// Kernel 3: score. Grid 1024 (1D), XCD-chunked swizzle: each XCD's 128-block
// chunk = one batch-half (8 m-tiles x all 16 n-tiles): Q-panel 1MB + K 2MB
// fits its 4MB L2. S = Q@K^T; P = exp(S*scale) -> bf16 via LDS repack.
// ---------------------------------------------------------------------------
__global__ __launch_bounds__(256) void k_score(
    const unsigned short* __restrict__ qbf, const unsigned short* __restrict__ kbf,
    unsigned short* __restrict__ pbf)
{
    __shared__ __align__(16) unsigned short sh[SH128];

    int t = threadIdx.x;
    int sw = (blockIdx.x & 7) * 128 + (blockIdx.x >> 3);   // bijective
    int b = sw >> 8, r = sw & 255;
    int m0 = (r >> 4) * 128, n0 = (r & 15) * 128;          // m slow, n fast

    f32x4 acc[4][4] = {};
    gemm_core128_p3(qbf + (size_t)(b * 2048 + m0) * 512, 512,
                    kbf + (size_t)(b * 2048 + n0) * 512, 512,
                    512, sh, t, acc);

    int wave = t >> 6, lane = t & 63, c = lane & 15, quad = lane >> 4;
    int wm = (wave >> 1) * 64, wn = (wave & 1) * 64;
    const float scale = 0.044194173824159216f;    // 1/sqrt(512)

    #pragma unroll
    for (int mt = 0; mt < 4; mt++) {
        #pragma unroll
        for (int r2 = 0; r2 < 4; r2++) {
            int row = wm + mt * 16 + quad * 4 + r2;   // local 0..127
            #pragma unroll
            for (int nt = 0; nt < 4; nt++) {
                float p = __expf(acc[mt][nt][r2] * scale);
                sh[row * RP + wn + nt * 16 + c] = f2bf(p);
            }
        }
    }
    __syncthreads();
    int rr = t >> 1, hh = (t & 1) * 64;
    const s16x8* sp = (const s16x8*)(sh + rr * RP + hh);
    s16x8* dp = (s16x8*)(pbf + (size_t)(b * 2048 + m0 + rr) * 2048 + n0 + hh);
    s16x8 v[8];
    #pragma unroll
    for (int i = 0; i < 8; i++) v[i] = sp[i];
    #pragma unroll
    for (int i = 0; i < 8; i++) dp[i] = v[i];
}

// ---------------------------------------------------------------------------
// Kernel 4: output. O = P @ Vt^T / l. 128x64 tile, grid 512 (1D, swizzled).
// Depth-3 counted-vmcnt staging (3 loads/tile: vmcnt(6)/(3)/(0)).
// l computed in-kernel via 5th accumulator column with all-ones bf16 B.
// ---------------------------------------------------------------------------
__global__ __launch_bounds__(256) void k_out(
    const unsigned short* __restrict__ pbf, const unsigned short* __restrict__ vtbf,
    float* __restrict__ zout)
{
    __shared__ __align__(16) unsigned short sh[18432];   // 3 x 6144

    int t = threadIdx.x;
    int sw = (blockIdx.x & 7) * 64 + (blockIdx.x >> 3);  // bijective, 64/XCD
    int b = sw >> 7, r = sw & 127;
    int m0 = (r >> 3) * 128, n0 = (r & 7) * 64;

    const int wave = t >> 6, lane = t & 63;
    const int c = lane & 15, quad = lane >> 4;
    const int wm = (wave >> 1) * 64, wn = (wave & 1) * 32;
    const int srow = t >> 2;
    const int scol = (t & 3) * 8;

    const unsigned short* ga = pbf + (size_t)(b * 2048 + m0 + srow) * 2048 + scol;
    const unsigned short* gb = vtbf + (size_t)(b * 512 + n0 + srow) * 2048 + scol;

    s16x8 ones;
    #pragma unroll
    for (int i = 0; i < 8; i++) ones[i] = (short)0x3F80;    // bf16 1.0

    f32x4 acc[4][2] = {};
    f32x4 accl[4] = {};

    #pragma unroll
    for (int p = 0; p < 3; p++) {                 // prologue: tiles 0..2
        unsigned short* nb = sh + p * 6144;
        GLOAD_LDS16(ga + p * 32,             nb + t * 8);
        GLOAD_LDS16(ga + p * 32 + 64 * 2048, nb + 2048 + t * 8);
        GLOAD_LDS16(gb + p * 32,             nb + 4096 + t * 8);
    }

    int cur = 0;
    for (int i = 0; i < 64; i++) {
        int rem = 63 - i;
        if (rem >= 2)      asm volatile("s_waitcnt vmcnt(6)" ::: "memory");
        else if (rem == 1) asm volatile("s_waitcnt vmcnt(3)" ::: "memory");
        else               asm volatile("s_waitcnt vmcnt(0)" ::: "memory");
        __builtin_amdgcn_s_barrier();
        __builtin_amdgcn_sched_barrier(0);

        const unsigned short* buf = sh + cur * 6144;
        s16x8 af[4], bf[2];
        #pragma unroll
        for (int q = 0; q < 4; q++)
            af[q] = *(const s16x8*)(buf + (wm + q * 16 + c) * 32 + quad * 8);
        #pragma unroll
        for (int q = 0; q < 2; q++)
            bf[q] = *(const s16x8*)(buf + 4096 + (wn + q * 16 + c) * 32 + quad * 8);

        asm volatile("s_waitcnt lgkmcnt(0)" ::: "memory");
        __builtin_amdgcn_sched_barrier(0);

        #pragma unroll
        for (int mt = 0; mt < 4; mt++) {
            #pragma unroll
            for (int nt = 0; nt < 2; nt++)
                acc[mt][nt] = MFMA16(af[mt], bf[nt], acc[mt][nt]);
            accl[mt] = MFMA16(af[mt], ones, accl[mt]);
        }

        __builtin_amdgcn_s_barrier();
        __builtin_amdgcn_sched_barrier(0);

        if (i + 3 < 64) {
            unsigned short* nb = sh + cur * 6144;
            int kk = (i + 3) * 32;
            GLOAD_LDS16(ga + kk,             nb + t * 8);
            GLOAD_LDS16(ga + kk + 64 * 2048, nb + 2048 + t * 8);
            GLOAD_LDS16(gb + kk,             nb + 4096 + t * 8);
        }
        cur = (cur == 2) ? 0 : cur + 1;
    }

    #pragma unroll
    for (int mt = 0; mt < 4; mt++) {
        #pragma unroll
        for (int r2 = 0; r2 < 4; r2++) {
            int row = wm + mt * 16 + quad * 4 + r2;
            float inv = 1.0f / accl[mt][r2];
            #pragma unroll
            for (int nt = 0; nt < 2; nt++) {
                zout[(size_t)(b * 2048 + m0 + row) * 512 + n0 + wn + nt * 16 + c]
                    = acc[mt][nt][r2] * inv;
            }
        }
    }
}

// ---------------------------------------------------------------------------
// Kernel 5 (fallback): standalone prior. Grid 2048, 4 rows/block.
// ---------------------------------------------------------------------------
__global__ __launch_bounds__(256) void k_prior(
    const float* __restrict__ x, const float* __restrict__ wsv,
    float* __restrict__ pout)
{
    int row = blockIdx.x * 4 + (threadIdx.x >> 6);
    prior_wave(x, wsv, pout, row, threadIdx.x & 63);
}

// ---------------------------------------------------------------------------
extern "C" void kernel_launch(void* const* d_in, const int* in_sizes, int n_in,
                              void* d_out, int out_size, void* d_ws, size_t ws_size,
                              hipStream_t stream)
{
    const float* x  = (const float*)d_in[0];
    const float* wq = (const float*)d_in[1];
    const float* wk = (const float*)d_in[2];
    const float* wv = (const float*)d_in[3];
    const float* ws = (const float*)d_in[4];

    float* zout = (float*)d_out;                       // (4,2048,512)
    float* pout = zout + (size_t)4 * 2048 * 512;       // (4,2048,2048) = 67.1 MB

    // Scratch: xbf 4.19M + wt 0.79M + q/k/vt 3*4.19M + pbf 16.78M ushorts.
    const size_t need = ((size_t)4194304 + 786432 + 3 * 4194304 + 16777216) * 2;

    if (ws_size >= need) {
        // ---- ws path: all scratch in d_ws; pout free -> prior overlaps convert
        unsigned short* base = (unsigned short*)d_ws;
        unsigned short* xbf  = base;
        unsigned short* wt   = xbf  + (size_t)4194304;
        unsigned short* qbf  = wt   + (size_t)786432;
        unsigned short* kbf  = qbf  + (size_t)4194304;
        unsigned short* vtbf = kbf  + (size_t)4194304;
        unsigned short* pbf  = vtbf + (size_t)4194304;

        k_convert_prior<<<dim3(6336), dim3(256), 0, stream>>>(
            x, wq, wk, wv, xbf, wt, ws, pout);
        k_proj <<<dim3(768),  dim3(256), 0, stream>>>(xbf, wt, qbf, kbf, vtbf);
        k_score<<<dim3(1024), dim3(256), 0, stream>>>(qbf, kbf, pbf);
        k_out  <<<dim3(512),  dim3(256), 0, stream>>>(pbf, vtbf, zout);
    } else {
        // ---- fallback: scratch inside pout (prior runs last)
        unsigned short* base = (unsigned short*)pout;
        unsigned short* pbf  = base;                        // 16,777,216
        unsigned short* qbf  = base + (size_t)16777216;
        unsigned short* kbf  = qbf  + (size_t)4194304;
        unsigned short* vtbf = kbf  + (size_t)4194304;
        unsigned short* xbf  = base;                        // overlaps pbf (ok)
        unsigned short* wt   = base + (size_t)4194304;      // overlaps pbf (ok)

        k_convert<<<dim3(4288), dim3(256), 0, stream>>>(x, wq, wk, wv, xbf, wt);
        k_proj <<<dim3(768),  dim3(256), 0, stream>>>(xbf, wt, qbf, kbf, vtbf);
        k_score<<<dim3(1024), dim3(256), 0, stream>>>(qbf, kbf, pbf);
        k_out  <<<dim3(512),  dim3(256), 0, stream>>>(pbf, vtbf, zout);
        k_prior<<<dim3(2048), dim3(256), 0, stream>>>(x, ws, pout);
    }
}

// Round 9
// 191.376 us; speedup vs baseline: 1.0614x; 1.0614x over previous
//
#include <hip/hip_runtime.h>

typedef float f32x4 __attribute__((ext_vector_type(4)));
typedef short s16x8 __attribute__((ext_vector_type(8)));
typedef unsigned short us4 __attribute__((ext_vector_type(4)));

#define MFMA16(a, b, c) __builtin_amdgcn_mfma_f32_16x16x32_bf16(a, b, c, 0, 0, 0)

// async global->LDS DMA, 16B per lane. LDS dest must be wave-uniform base + lane*16.
#define GLOAD_LDS16(gp, lp) __builtin_amdgcn_global_load_lds( \
    (__attribute__((address_space(1))) void*)(gp),            \
    (__attribute__((address_space(3))) void*)(lp), 16, 0, 0)

__device__ __forceinline__ unsigned short f2bf(float f) {
    union { float f; unsigned u; } v; v.f = f;
    unsigned r = v.u + 0x7fffu + ((v.u >> 16) & 1u);   // RNE truncate to bf16
    return (unsigned short)(r >> 16);
}

// ---------------------------------------------------------------------------
// 256x256-tile GEMM core, 8 waves (512 thr), BK=32, depth-2 counted vmcnt.
// C += A[256xK] @ B[256xK]^T. Wave w: rows [ (w>>2)*128, +128 ), cols
// [ (w&3)*64, +64 ) -> acc[8][4] 16x16 frags. 32 MFMA per barrier-pair/wave.
//   iter i: vmcnt(4) [tile i landed] ; barrier ; 12 ds_read_b128 ;
//           lgkmcnt(0)+sched_barrier ; 32 MFMA ; barrier ; stage tile i+2.
// LDS: 2 buffers x 16384 shorts (A [256][32] @0, B [256][32] @8192) = 64KB.
// R8-VERIFIED NUMERICALLY CORRECT (Z output passed).
// ---------------------------------------------------------------------------
__device__ __forceinline__ void gemm_core256(
    const unsigned short* __restrict__ Ab, size_t Astride,
    const unsigned short* __restrict__ Bb, size_t Bstride,
    int K, unsigned short* sh, int t, f32x4 acc[8][4])
{
    const int w = t >> 6, lane = t & 63;
    const int c = lane & 15, quad = lane >> 4;
    const int arow = (w >> 2) * 128;      // wave's A-row base (0 or 128)
    const int brow = (w & 3) * 64;        // wave's B-row base (0..192)
    const int srow = t >> 2;              // 0..127 staging row
    const int scol = (t & 3) * 8;

    const unsigned short* ga = Ab + (size_t)srow * Astride + scol;
    const unsigned short* gb = Bb + (size_t)srow * Bstride + scol;
    const int ntil = K >> 5;

#define STAGE256(p, bbuf) do {                                      \
        unsigned short* nb = sh + (bbuf) * 16384;                   \
        int kk = (p) * 32;                                          \
        GLOAD_LDS16(ga + kk,                 nb + t * 8);           \
        GLOAD_LDS16(ga + kk + 128 * Astride, nb + 4096 + t * 8);    \
        GLOAD_LDS16(gb + kk,                 nb + 8192 + t * 8);    \
        GLOAD_LDS16(gb + kk + 128 * Bstride, nb + 12288 + t * 8);   \
    } while (0)

    // prologue: tiles 0,1 -> bufs 0,1 (8 loads/thread outstanding)
    STAGE256(0, 0);
    STAGE256(1, 1);

    int cur = 0;
    for (int i = 0; i < ntil; i++) {
        if (i + 1 < ntil) asm volatile("s_waitcnt vmcnt(4)" ::: "memory");
        else              asm volatile("s_waitcnt vmcnt(0)" ::: "memory");
        __builtin_amdgcn_s_barrier();              // tile i visible to all
        __builtin_amdgcn_sched_barrier(0);

        const unsigned short* buf = sh + cur * 16384;
        s16x8 af[8], bf[4];
        #pragma unroll
        for (int q = 0; q < 8; q++)
            af[q] = *(const s16x8*)(buf + (arow + q * 16 + c) * 32 + quad * 8);
        #pragma unroll
        for (int q = 0; q < 4; q++)
            bf[q] = *(const s16x8*)(buf + 8192 + (brow + q * 16 + c) * 32 + quad * 8);

        asm volatile("s_waitcnt lgkmcnt(0)" ::: "memory");
        __builtin_amdgcn_sched_barrier(0);         // rule #18: pin MFMA below

        #pragma unroll
        for (int mt = 0; mt < 8; mt++)
            #pragma unroll
            for (int nt = 0; nt < 4; nt++)
                acc[mt][nt] = MFMA16(af[mt], bf[nt], acc[mt][nt]);

        __builtin_amdgcn_s_barrier();              // all reads of buf retired
        __builtin_amdgcn_sched_barrier(0);

        if (i + 2 < ntil) STAGE256(i + 2, cur);    // refill freed buffer
        cur ^= 1;
    }
#undef STAGE256
}

// ---------------------------------------------------------------------------
// prior: one WAVE per (b,i) row — no LDS, no barriers, no atomics.
// ---------------------------------------------------------------------------
__device__ __forceinline__ void prior_wave(
    const float* __restrict__ x, const float* __restrict__ wsv,
    float* __restrict__ pout, int row, int lane)
{
    const float4* xr = (const float4*)(x + (size_t)row * 512);
    const float4* wr = (const float4*)wsv;
    float4 a0 = xr[lane * 2],     b0 = wr[lane * 2];
    float4 a1 = xr[lane * 2 + 1], b1 = wr[lane * 2 + 1];
    float part = a0.x * b0.x + a0.y * b0.y + a0.z * b0.z + a0.w * b0.w
               + a1.x * b1.x + a1.y * b1.y + a1.z * b1.z + a1.w * b1.w;
    #pragma unroll
    for (int o = 32; o; o >>= 1) part += __shfl_xor(part, o, 64);
    float sigma = part;
    float inv2 = 0.5f / (sigma * sigma);

    int i = row & 2047;
    float g[32];
    float sum = 0.f;
    #pragma unroll
    for (int u = 0; u < 8; u++) {
        #pragma unroll
        for (int v = 0; v < 4; v++) {
            float d = (float)(u * 256 + lane * 4 + v - i);
            float e = __expf(-(d * d) * inv2);
            g[u * 4 + v] = e;
            sum += e;
        }
    }
    #pragma unroll
    for (int o = 32; o; o >>= 1) sum += __shfl_xor(sum, o, 64);
    float inv = 1.0f / sum;

    float4* pr = (float4*)(pout + (size_t)row * 2048);
    #pragma unroll
    for (int u = 0; u < 8; u++) {
        float4 o4 = { g[u * 4] * inv, g[u * 4 + 1] * inv,
                      g[u * 4 + 2] * inv, g[u * 4 + 3] * inv };
        pr[u * 64 + lane] = o4;
    }
}

// ---------------------------------------------------------------------------
// Kernel 1: convert x -> bf16 row-major; W{q,k,v} -> bf16 transposed [n][k]
// via 64x64 LDS-transpose tiles. Grid 4288: [0,4096) x, [4096,4288) weights.
// (R6-verified, unchanged.)
// ---------------------------------------------------------------------------
__global__ __launch_bounds__(256) void k_convert(
    const float* __restrict__ x, const float* __restrict__ wq,
    const float* __restrict__ wk, const float* __restrict__ wv,
    unsigned short* __restrict__ xbf, unsigned short* __restrict__ wt)
{
    __shared__ __align__(16) unsigned short lt[64][72];   // 64x64 tile, padded

    int bid = blockIdx.x, t = threadIdx.x;
    if (bid < 4096) {
        int gid = bid * 256 + t;
        float4 v = ((const float4*)x)[gid];
        us4 o = { f2bf(v.x), f2bf(v.y), f2bf(v.z), f2bf(v.w) };
        ((us4*)xbf)[gid] = o;
    } else {
        int idx = bid - 4096;
        int w = idx >> 6;                    // 0=q 1=k 2=v
        int tile = idx & 63;
        int tk = tile >> 3, tn = tile & 7;   // 8x8 tiles of 64x64 over [512][512]
        const float* src = ((w == 0) ? wq : (w == 1) ? wk : wv)
                         + (size_t)(tk * 64) * 512 + tn * 64;

        int row = t >> 2;
        int c0 = (t & 3) * 16;
        const float4* s = (const float4*)(src + (size_t)row * 512 + c0);
        #pragma unroll
        for (int q = 0; q < 4; q++) {
            float4 v = s[q];
            lt[c0 + q * 4 + 0][row] = f2bf(v.x);
            lt[c0 + q * 4 + 1][row] = f2bf(v.y);
            lt[c0 + q * 4 + 2][row] = f2bf(v.z);
            lt[c0 + q * 4 + 3][row] = f2bf(v.w);
        }
        __syncthreads();

        int n = t >> 2;
        int k0 = (t & 3) * 16;
        s16x8 a = *(const s16x8*)&lt[n][k0];
        s16x8 b = *(const s16x8*)&lt[n][k0 + 8];
        unsigned short* dst = wt + (((size_t)(w * 512 + tn * 64 + n)) << 9)
                                 + tk * 64 + k0;
        *(s16x8*)dst = a;
        *(s16x8*)(dst + 8) = b;
    }
}

// ---------------------------------------------------------------------------
// Kernel 2: QKV projection. [8192x512] @ [1536x512]^T. Grid 192 (32m x 6n of
// 256^2 tiles). 512 threads. Direct stores (R8-verified).
// ---------------------------------------------------------------------------
__global__ __launch_bounds__(512, 2) void k_proj(
    const unsigned short* __restrict__ xbf, const unsigned short* __restrict__ wt,
    unsigned short* __restrict__ qbf, unsigned short* __restrict__ kbf,
    unsigned short* __restrict__ vtbf)
{
    __shared__ __align__(16) unsigned short sh[32768];   // 64KB: 2 x 16384

    int t = threadIdx.x;
    int mt_ = blockIdx.x / 6, nt_ = blockIdx.x % 6;
    int m0 = mt_ * 256, n0 = nt_ * 256;

    f32x4 acc[8][4] = {};
    gemm_core256(xbf + (size_t)m0 * 512, 512, wt + (size_t)n0 * 512, 512,
                 512, sh, t, acc);

    int w = t >> 6, lane = t & 63, c = lane & 15, quad = lane >> 4;
    int wr = w >> 2, wc = w & 3;
    int sel = nt_ >> 1;                           // 0=q 1=k 2=v

    if (sel < 2) {
        unsigned short* dst = sel ? kbf : qbf;
        int ncol0 = n0 - sel * 512;
        #pragma unroll
        for (int mt = 0; mt < 8; mt++) {
            #pragma unroll
            for (int nt = 0; nt < 4; nt++) {
                int col = ncol0 + wc * 64 + nt * 16 + c;
                #pragma unroll
                for (int r = 0; r < 4; r++) {
                    int rw = m0 + wr * 128 + mt * 16 + quad * 4 + r;
                    dst[(size_t)rw * 512 + col] = f2bf(acc[mt][nt][r]);
                }
            }
        }
    } else {
        // V: Vt[b][d][n] us4-packed over 4 consecutive m (R8-verified)
        #pragma unroll
        for (int mt = 0; mt < 8; mt++) {
            int rw0 = m0 + wr * 128 + mt * 16 + quad * 4;
            int bb = rw0 >> 11, nn = rw0 & 2047;
            #pragma unroll
            for (int nt = 0; nt < 4; nt++) {
                int d = (n0 - 1024) + wc * 64 + nt * 16 + c;
                us4 pk = { f2bf(acc[mt][nt][0]), f2bf(acc[mt][nt][1]),
                           f2bf(acc[mt][nt][2]), f2bf(acc[mt][nt][3]) };
                *(us4*)(vtbf + ((size_t)(bb * 512 + d)) * 2048 + nn) = pk;
            }
        }
    }
}

// ---------------------------------------------------------------------------
// score body: 256x256 tile of S = Q@K^T; P = exp(S*scale) -> bf16 direct
// stores. No l accumulation — k_out self-computes it. (R8-verified.)
// ---------------------------------------------------------------------------
__device__ __forceinline__ void score_body(
    const unsigned short* __restrict__ qbf, const unsigned short* __restrict__ kbf,
    unsigned short* __restrict__ pbf,
    int b, int m0, int n0, int t, unsigned short* sh)
{
    f32x4 acc[8][4] = {};
    gemm_core256(qbf + (size_t)(b * 2048 + m0) * 512, 512,
                 kbf + (size_t)(b * 2048 + n0) * 512, 512,
                 512, sh, t, acc);

    int w = t >> 6, lane = t & 63, c = lane & 15, quad = lane >> 4;
    int wr = w >> 2, wc = w & 3;
    const float scale = 0.044194173824159216f;    // 1/sqrt(512)

    #pragma unroll
    for (int mt = 0; mt < 8; mt++) {
        #pragma unroll
        for (int nt = 0; nt < 4; nt++) {
            int col = n0 + wc * 64 + nt * 16 + c;
            #pragma unroll
            for (int r = 0; r < 4; r++) {
                int row = m0 + wr * 128 + mt * 16 + quad * 4 + r;
                pbf[(size_t)(b * 2048 + row) * 2048 + col]
                    = f2bf(__expf(acc[mt][nt][r] * scale));
            }
        }
    }
}

// ---------------------------------------------------------------------------
// Kernel 3a (ws path): merged score + prior. Grid 1280 (512 thr):
// [0,256) score: b = bid>>6, m-tile = (bid>>3)&7, n-tile = bid&7 (256^2);
// [256,1280) prior: 1024 blocks x 8 rows/block (wave-per-row) = 8192 rows.
// (R8 BUG FIX: prior coverage was 2048 rows, needs 8192.)
// ---------------------------------------------------------------------------
__global__ __launch_bounds__(512, 2) void k_score_prior(
    const unsigned short* __restrict__ qbf, const unsigned short* __restrict__ kbf,
    unsigned short* __restrict__ pbf,
    const float* __restrict__ x, const float* __restrict__ wsv,
    float* __restrict__ pout)
{
    __shared__ __align__(16) unsigned short sh[32768];

    int bid = blockIdx.x, t = threadIdx.x;
    if (bid < 256) {
        int b = bid >> 6, r = bid & 63;
        score_body(qbf, kbf, pbf, b, ((r >> 3) & 7) * 256, (r & 7) * 256, t, sh);
    } else {
        int row = (bid - 256) * 8 + (t >> 6);     // 1024 blocks x 8 = 8192 rows
        prior_wave(x, wsv, pout, row, t & 63);
    }
}

// ---------------------------------------------------------------------------
// Kernel 3b (fallback): standalone score. Grid 256, 512 thr.
// ---------------------------------------------------------------------------
__global__ __launch_bounds__(512, 2) void k_score(
    const unsigned short* __restrict__ qbf, const unsigned short* __restrict__ kbf,
    unsigned short* __restrict__ pbf)
{
    __shared__ __align__(16) unsigned short sh[32768];
    int bid = blockIdx.x;
    int b = bid >> 6, r = bid & 63;
    score_body(qbf, kbf, pbf, b, ((r >> 3) & 7) * 256, (r & 7) * 256,
               threadIdx.x, sh);
}

// ---------------------------------------------------------------------------
// Kernel 4: output. O = P @ Vt^T / l. 128x64 tile, grid (16,8,4).
// R6-verified counted-vmcnt depth-2 staging. l via ones-fragment MFMA.
// ---------------------------------------------------------------------------
__global__ __launch_bounds__(256) void k_out(
    const unsigned short* __restrict__ pbf, const unsigned short* __restrict__ vtbf,
    float* __restrict__ zout)
{
    __shared__ __align__(16) unsigned short sh[12288];

    int t = threadIdx.x;
    int b = blockIdx.z;
    int m0 = blockIdx.x * 128, n0 = blockIdx.y * 64;

    const int wave = t >> 6, lane = t & 63;
    const int c = lane & 15, quad = lane >> 4;
    const int wm = (wave >> 1) * 64, wn = (wave & 1) * 32;
    const int srow = t >> 2;
    const int scol = (t & 3) * 8;

    const unsigned short* ga = pbf + (size_t)(b * 2048 + m0 + srow) * 2048 + scol;
    const unsigned short* gb = vtbf + (size_t)(b * 512 + n0 + srow) * 2048 + scol;

    s16x8 ones;
    #pragma unroll
    for (int i = 0; i < 8; i++) ones[i] = (short)0x3F80;    // bf16 1.0

    f32x4 acc[4][2] = {};
    f32x4 accl[4] = {};

    // prologue: tile0 -> buf0, tile1 -> buf1 (vmcnt = 6)
    GLOAD_LDS16(ga,                  sh + t * 8);
    GLOAD_LDS16(ga + 64 * 2048,      sh + 2048 + t * 8);
    GLOAD_LDS16(gb,                  sh + 4096 + t * 8);
    GLOAD_LDS16(ga + 32,             sh + 6144 + t * 8);
    GLOAD_LDS16(ga + 32 + 64 * 2048, sh + 6144 + 2048 + t * 8);
    GLOAD_LDS16(gb + 32,             sh + 6144 + 4096 + t * 8);

    int cur = 0;
    for (int k0 = 0; k0 < 2048; k0 += 32) {
        if (k0 + 32 < 2048) asm volatile("s_waitcnt vmcnt(3)" ::: "memory");
        else                asm volatile("s_waitcnt vmcnt(0)" ::: "memory");
        __builtin_amdgcn_s_barrier();
        __builtin_amdgcn_sched_barrier(0);

        const unsigned short* buf = sh + cur * 6144;
        s16x8 af[4], bf[2];
        #pragma unroll
        for (int i = 0; i < 4; i++)
            af[i] = *(const s16x8*)(buf + (wm + i * 16 + c) * 32 + quad * 8);
        #pragma unroll
        for (int i = 0; i < 2; i++)
            bf[i] = *(const s16x8*)(buf + 4096 + (wn + i * 16 + c) * 32 + quad * 8);

        asm volatile("s_waitcnt lgkmcnt(0)" ::: "memory");
        __builtin_amdgcn_sched_barrier(0);

        #pragma unroll
        for (int mt = 0; mt < 4; mt++) {
            #pragma unroll
            for (int nt = 0; nt < 2; nt++)
                acc[mt][nt] = MFMA16(af[mt], bf[nt], acc[mt][nt]);
            accl[mt] = MFMA16(af[mt], ones, accl[mt]);
        }

        __builtin_amdgcn_s_barrier();
        __builtin_amdgcn_sched_barrier(0);

        if (k0 + 64 < 2048) {
            unsigned short* nb = sh + cur * 6144;
            GLOAD_LDS16(ga + k0 + 64,             nb + t * 8);
            GLOAD_LDS16(ga + k0 + 64 + 64 * 2048, nb + 2048 + t * 8);
            GLOAD_LDS16(gb + k0 + 64,             nb + 4096 + t * 8);
        }
        cur ^= 1;
    }

    #pragma unroll
    for (int mt = 0; mt < 4; mt++) {
        #pragma unroll
        for (int r = 0; r < 4; r++) {
            int row = wm + mt * 16 + quad * 4 + r;
            float inv = 1.0f / accl[mt][r];
            #pragma unroll
            for (int nt = 0; nt < 2; nt++) {
                zout[(size_t)(b * 2048 + m0 + row) * 512 + n0 + wn + nt * 16 + c]
                    = acc[mt][nt][r] * inv;
            }
        }
    }
}

// ---------------------------------------------------------------------------
// Kernel 5 (fallback): standalone prior. Grid 1024, 512 thr, 8 rows/block.
// ---------------------------------------------------------------------------
__global__ __launch_bounds__(512) void k_prior(
    const float* __restrict__ x, const float* __restrict__ wsv,
    float* __restrict__ pout)
{
    int row = blockIdx.x * 8 + (threadIdx.x >> 6);
    prior_wave(x, wsv, pout, row, threadIdx.x & 63);
}

// ---------------------------------------------------------------------------
extern "C" void kernel_launch(void* const* d_in, const int* in_sizes, int n_in,
                              void* d_out, int out_size, void* d_ws, size_t ws_size,
                              hipStream_t stream)
{
    const float* x  = (const float*)d_in[0];
    const float* wq = (const float*)d_in[1];
    const float* wk = (const float*)d_in[2];
    const float* wv = (const float*)d_in[3];
    const float* ws = (const float*)d_in[4];

    float* zout = (float*)d_out;                       // (4,2048,512)
    float* pout = zout + (size_t)4 * 2048 * 512;       // (4,2048,2048) = 67.1 MB

    // Scratch: xbf 4.19M + wt 0.79M + q/k/vt 3*4.19M + pbf 16.78M ushorts.
    const size_t need = ((size_t)4194304 + 786432 + 3 * 4194304 + 16777216) * 2;

    if (ws_size >= need) {
        // ---- ws path: all scratch in d_ws; pout free -> prior overlaps score
        unsigned short* base = (unsigned short*)d_ws;
        unsigned short* xbf  = base;
        unsigned short* wt   = xbf  + (size_t)4194304;
        unsigned short* qbf  = wt   + (size_t)786432;
        unsigned short* kbf  = qbf  + (size_t)4194304;
        unsigned short* vtbf = kbf  + (size_t)4194304;
        unsigned short* pbf  = vtbf + (size_t)4194304;

        k_convert<<<dim3(4288), dim3(256), 0, stream>>>(x, wq, wk, wv, xbf, wt);
        k_proj       <<<dim3(192),      dim3(512), 0, stream>>>(xbf, wt, qbf, kbf, vtbf);
        k_score_prior<<<dim3(1280),     dim3(512), 0, stream>>>(qbf, kbf, pbf, x, ws, pout);
        k_out        <<<dim3(16, 8, 4), dim3(256), 0, stream>>>(pbf, vtbf, zout);
    } else {
        // ---- fallback: scratch inside pout (prior runs last)
        unsigned short* base = (unsigned short*)pout;
        unsigned short* pbf  = base;                        // 16,777,216
        unsigned short* qbf  = base + (size_t)16777216;
        unsigned short* kbf  = qbf  + (size_t)4194304;
        unsigned short* vtbf = kbf  + (size_t)4194304;
        unsigned short* xbf  = base;                        // overlaps pbf (ok)
        unsigned short* wt   = base + (size_t)4194304;      // overlaps pbf (ok)

        k_convert<<<dim3(4288), dim3(256), 0, stream>>>(x, wq, wk, wv, xbf, wt);
        k_proj <<<dim3(192),      dim3(512), 0, stream>>>(xbf, wt, qbf, kbf, vtbf);
        k_score<<<dim3(256),      dim3(512), 0, stream>>>(qbf, kbf, pbf);
        k_out  <<<dim3(16, 8, 4), dim3(256), 0, stream>>>(pbf, vtbf, zout);
        k_prior<<<dim3(1024),     dim3(512), 0, stream>>>(x, ws, pout);
    }
}